// Round 8
// baseline (463.359 us; speedup 1.0000x reference)
//
#include <hip/hip_runtime.h>

// LRU forward, MI355X/gfx950.
// Pipeline: prep (lambda/gamma/Bcat/Ccat/bf16-inputs) -> GEMM1 (Bu) ->
// chunked scan (64 chunks of 64, carry fix-up, in-place hs) -> GEMM2 (+skip).
// History: R5/R6/R9/R10 intra-block schedule variants ALL pin at 33-37%
// MfmaUtil == serial DS(1505 incl glds-writes) + MFMA(1242) per K-tile.
// Root cause: single 8-wave block is barrier-locked phase-synchronous; DS
// round-robin makes all waves' reads finish together -> MFMA entry is
// synchronized -> zero cross-pipe overlap, regardless of read placement.
// R11: INTER-BLOCK CO-SCHEDULING (m114 mechanism): BM=256 BN=128, 4 waves,
// ring-2 LDS (48KB/block) -> 2 independent blocks/CU. Block A's MFMA fills
// block B's read/barrier phases with no sync coupling. 256-thread blocks at
// 8 waves/CU have a 256-reg/wave budget vs ~140 demand -> the hard-cap spill
// fragility of the 512-thread design (R7/R8 failures) is structurally gone.
// Per-wave tile (128x64), frags, acc, MFMA clusters: verbatim R10.
// Body: STAGE6(kt+1)->RD_A47->lgkm(4)->MFMA16(0)->lgkm(0)->MFMA16(4)->
// vmcnt(0) [stage issued ~1300cyc earlier; A/B tiles L2-resident]->BAR->
// RD_B/RD_A03(next) [post-barrier lookahead, drain under next body's top].
// All cross-wave LDS reads follow the vmcnt(0)+BAR cert of their tile. WAR:
// stage into slot kt&1^1 follows >=1 barrier after that slot's last reads.
// R11 also re-lands the scan vectorization (x2-h uint loads, L=64, lamL=
// lambda^64) that R7 bundled with its failed GEMM.

typedef __bf16 bf16x8 __attribute__((ext_vector_type(8)));
typedef float floatx4 __attribute__((ext_vector_type(4)));

__device__ __forceinline__ unsigned short f2bf(float f) {
  unsigned u = __float_as_uint(f);
  u += 0x7fffu + ((u >> 16) & 1u);   // RNE; inputs are finite
  return (unsigned short)(u >> 16);
}
__device__ __forceinline__ float bf2f(unsigned short s) {
  return __uint_as_float(((unsigned)s) << 16);
}

// ---------------- prep kernels ----------------

__global__ void prep_params(const float* __restrict__ nu_log,
                            const float* __restrict__ theta_log,
                            float* __restrict__ lam,    // [2048] re|im
                            float* __restrict__ lamL,   // [2048] lambda^64 re|im
                            float* __restrict__ gamma)  // [1024]
{
  int h = blockIdx.x * 256 + threadIdx.x;   // exactly 1024
  float nu = expf(nu_log[h]);
  float th = expf(theta_log[h]);
  float r = expf(-nu);
  lam[h]        = r * cosf(th);
  lam[1024 + h] = r * sinf(th);
  float rL = expf(-64.0f * nu);              // chunk length L=64
  lamL[h]        = rL * cosf(64.0f * th);
  lamL[1024 + h] = rL * sinf(64.0f * th);
  gamma[h] = sqrtf(1.0f - expf(-2.0f * nu) + 1e-5f);
}

__global__ void prep_B(const float* __restrict__ B_re, const float* __restrict__ B_im,
                       const float* __restrict__ gamma, unsigned short* __restrict__ Bcat)
{
  int tid = blockIdx.x * 256 + threadIdx.x;  // 2048*1024
  int n = tid >> 10;
  int d = tid & 1023;
  int h = n & 1023;
  float v = (n < 1024 ? B_re[h * 1024 + d] : B_im[h * 1024 + d]) * gamma[h];
  Bcat[tid] = f2bf(v);
}

__global__ void prep_C(const float* __restrict__ C_re, const float* __restrict__ C_im,
                       unsigned short* __restrict__ Ccat)
{
  int tid = blockIdx.x * 256 + threadIdx.x;  // 1024*2048
  int d = tid >> 11;
  int k = tid & 2047;
  float v = (k < 1024) ? C_re[d * 1024 + k] : -C_im[d * 1024 + (k - 1024)];
  Ccat[tid] = f2bf(v);
}

__global__ void conv_inputs(const float* __restrict__ in, unsigned short* __restrict__ outb)
{
  int tid = blockIdx.x * 256 + threadIdx.x;  // 16.7M/4
  float4 v = ((const float4*)in)[tid];
  unsigned lo = (unsigned)f2bf(v.x) | ((unsigned)f2bf(v.y) << 16);
  unsigned hi = (unsigned)f2bf(v.z) | ((unsigned)f2bf(v.w) << 16);
  ((uint2*)outb)[tid] = make_uint2(lo, hi);
}

// ---------------- GEMM (A: [M,K] k-contig, Bt: [N,K] k-contig) ----------------
// 256x128 tile, BK=32, 4 waves (2m x 2n), per-wave 128x64 via 8x4 16x16x32
// frags (32 MFMA / wave / K-tile in two 16-MFMA clusters).
// LDS: ring-2 x (A 16KB + B 8KB) = 48KB/block -> 2 blocks/CU (96KB, 8 waves).
// LDS swizzle (measured conflict-free): row r (64B) holds its four 16B
// k-chunks at position p storing logical chunk p ^ ((r>>1)&3).
// XCD-compact swizzle: xcd=id&7 owns m-tiles [xcd*8, xcd*8+8), m-fastest.
// Staging: 6 glds/thread/K-tile (A: 4 rounds of 64 rows, B: 2 rounds), dest
// = wave-uniform + lane*16B (glds-linear); source chunk pre-swizzled.

#define GLDS(gp, lp) __builtin_amdgcn_global_load_lds(                        \
      (const __attribute__((address_space(1))) void*)(gp),                    \
      (__attribute__((address_space(3))) void*)(lp), 16, 0, 0)

// Stage tile kt into ring slot S (A: rows 0..255 in 4 rounds; B: 128 in 2).
#define STAGE6(kt, S) do {                                                    \
    const int _ko = (kt) * 32;                                                \
    GLDS(gA0 + _ko, &As[(S)][dA0]);                                           \
    GLDS(gA1 + _ko, &As[(S)][dA1]);                                           \
    GLDS(gA2 + _ko, &As[(S)][dA2]);                                           \
    GLDS(gA3 + _ko, &As[(S)][dA3]);                                           \
    GLDS(gB0 + _ko, &Bs[(S)][dB0]);                                           \
    GLDS(gB1 + _ko, &Bs[(S)][dB1]);                                           \
  } while (0)

#define RD_B(S) do {                                                          \
    _Pragma("unroll")                                                         \
    for (int j = 0; j < 4; ++j) {                                             \
      const int r = wn * 64 + j * 16 + lm;                                    \
      bfr[j] = *reinterpret_cast<const bf16x8*>(                              \
          &Bs[(S)][r * 32 + (q ^ ((r >> 1) & 3)) * 8]);                       \
    }                                                                         \
  } while (0)

#define RD_A(S, i0) do {                                                      \
    _Pragma("unroll")                                                         \
    for (int i = 0; i < 4; ++i) {                                             \
      const int r = wm * 128 + ((i0) + i) * 16 + lm;                          \
      afr[(i0) + i] = *reinterpret_cast<const bf16x8*>(                       \
          &As[(S)][r * 32 + (q ^ ((r >> 1) & 3)) * 8]);                       \
    }                                                                         \
  } while (0)

#define MFMA16(i0) do {                                                       \
    __builtin_amdgcn_s_setprio(1);                                            \
    _Pragma("unroll")                                                         \
    for (int i = 0; i < 4; ++i)                                               \
      _Pragma("unroll")                                                       \
      for (int j = 0; j < 4; ++j)                                             \
        acc[(i0) + i][j] = __builtin_amdgcn_mfma_f32_16x16x32_bf16(           \
            afr[(i0) + i], bfr[j], acc[(i0) + i][j], 0, 0, 0);                \
    __builtin_amdgcn_s_setprio(0);                                            \
  } while (0)

#define SB0() __builtin_amdgcn_sched_barrier(0)

#define VMW0() do {                                                           \
    SB0();                                                                    \
    asm volatile("s_waitcnt vmcnt(0)" ::: "memory");                          \
    SB0();                                                                    \
  } while (0)

#define LGKMC(n) do {                                                         \
    SB0();                                                                    \
    asm volatile("s_waitcnt lgkmcnt(" #n ")" ::: "memory");                   \
    SB0();                                                                    \
  } while (0)

#define BAR() do {                                                            \
    SB0();                                                                    \
    asm volatile("" ::: "memory");                                            \
    __builtin_amdgcn_s_barrier();                                             \
    asm volatile("" ::: "memory");                                            \
    SB0();                                                                    \
  } while (0)

// Full body for K-tile kt_ (ring slot C), staging kt_+1 into slot N, with
// post-barrier lookahead reads of slot N for the next body.
#define BODY(kt_, C, N) do {                                                  \
    STAGE6((kt_) + 1, N);                                                     \
    RD_A(C, 4);                                                               \
    LGKMC(4);        /* drains prev body's 8 lookahead reads */               \
    MFMA16(0);                                                                \
    LGKMC(0);        /* afr47 drained (under MFMA16(0)) */                    \
    MFMA16(4);                                                                \
    VMW0();          /* stage(kt_+1) landed (~1300cyc gap, L2-resident) */    \
    BAR();           /* block-wide cert + WAR fence */                        \
    RD_B(N);                                                                  \
    RD_A(N, 0);      /* lookahead for next body; drain under its top */       \
  } while (0)

template <int EPI>
__global__ __launch_bounds__(256) void gemm256_kernel(
    const unsigned short* __restrict__ A,
    const unsigned short* __restrict__ Bt,
    void* __restrict__ Cout,
    int M, int N, int K,
    const float* __restrict__ skip_in,
    const float* __restrict__ skip_w)
{
  __shared__ __align__(16) unsigned short As[2][256 * 32];
  __shared__ __align__(16) unsigned short Bs[2][128 * 32];

  const int tid  = threadIdx.x;
  const int lane = tid & 63;
  const int wave = tid >> 6;   // 0..3
  const int wm = wave >> 1;    // 0..1 (m half: 128 rows)
  const int wn = wave & 1;     // 0..1 (n half: 64 cols)

  // XCD-compact tile assignment: m-inner 8 tiles per XCD, n outer.
  // GEMM1: 64 m x 16 n = 1024 blocks; GEMM2: 64 m x 8 n = 512. Both %8==0.
  const int flat    = blockIdx.x;
  const int xcd     = flat & 7;
  const int local   = flat >> 3;
  const int m_tile  = xcd * 8 + (local & 7);
  const int n_tile  = local >> 3;
  const int m0 = m_tile * 256;
  const int n0 = n_tile * 128;

  const int ldr = lane >> 2;   // 0..15: row within a 16-row staging group
  const int pos = lane & 3;    // 16B chunk position within the 64B row
  const int lm  = lane & 15;   // fragment row (A: m, B: n)
  const int q   = lane >> 4;   // fragment k-chunk (k = q*8 + j)

  // Staging rows: wave w covers rows w*16+ldr (+64 per round).
  const int rs = wave * 16 + ldr;
  // A rounds j=0..3 rows rs+64j; B rounds j=0..1 rows rs+64j.
  const int rA0 = rs,      rA1 = rs + 64, rA2 = rs + 128, rA3 = rs + 192;
  const int rB0 = rs,      rB1 = rs + 64;
  const int cA0 = pos ^ ((rA0 >> 1) & 3), cA1 = pos ^ ((rA1 >> 1) & 3);
  const int cA2 = pos ^ ((rA2 >> 1) & 3), cA3 = pos ^ ((rA3 >> 1) & 3);
  const int cB0 = pos ^ ((rB0 >> 1) & 3), cB1 = pos ^ ((rB1 >> 1) & 3);

  const unsigned short* gA0 = A  + (size_t)(m0 + rA0) * K + cA0 * 8;
  const unsigned short* gA1 = A  + (size_t)(m0 + rA1) * K + cA1 * 8;
  const unsigned short* gA2 = A  + (size_t)(m0 + rA2) * K + cA2 * 8;
  const unsigned short* gA3 = A  + (size_t)(m0 + rA3) * K + cA3 * 8;
  const unsigned short* gB0 = Bt + (size_t)(n0 + rB0) * K + cB0 * 8;
  const unsigned short* gB1 = Bt + (size_t)(n0 + rB1) * K + cB1 * 8;
  // LDS dests (elements): r*32 + pos*8 == wave-uniform + lane*8 elems (16B).
  const int dA0 = rA0 * 32 + pos * 8, dA1 = rA1 * 32 + pos * 8;
  const int dA2 = rA2 * 32 + pos * 8, dA3 = rA3 * 32 + pos * 8;
  const int dB0 = rB0 * 32 + pos * 8, dB1 = rB1 * 32 + pos * 8;

  floatx4 acc[8][4];
#pragma unroll
  for (int i = 0; i < 8; ++i)
#pragma unroll
    for (int j = 0; j < 4; ++j)
      acc[i][j] = (floatx4){0.f, 0.f, 0.f, 0.f};

  const int KT = K >> 5;   // 32 or 64 K-tiles; even, >= 4

  bf16x8 afr[8], bfr[4];

  // Prologue: stage tile 0 into slot 0; full drain (one-time); lookahead
  // reads for body 0.
  STAGE6(0, 0);
  VMW0();
  BAR();
  RD_B(0);
  RD_A(0, 0);

  // Bodies 0..KT-2 (2x unrolled for compile-time ring slots); KT even.
  for (int kt = 0; kt + 2 < KT; kt += 2) {
    BODY(kt,     0, 1);
    BODY(kt + 1, 1, 0);
  }
  BODY(KT - 2, 0, 1);          // stages and certifies tile KT-1
  {                            // final tile: no stage, no trailing reads
    RD_A(1, 4);
    LGKMC(4);
    MFMA16(0);
    LGKMC(0);
    MFMA16(4);
  }

  // Epilogue. C/D layout: col = lane&15, row = (lane>>4)*4 + reg.
#pragma unroll
  for (int i = 0; i < 8; ++i) {
#pragma unroll
    for (int j = 0; j < 4; ++j) {
      const int row0 = m0 + wm * 128 + i * 16 + q * 4;
      const int col  = n0 + wn * 64 + j * 16 + lm;
#pragma unroll
      for (int r = 0; r < 4; ++r) {
        const size_t idx = (size_t)(row0 + r) * N + col;
        if (EPI == 0) {
          ((unsigned short*)Cout)[idx] = f2bf(acc[i][j][r]);
        } else {
          ((float*)Cout)[idx] = acc[i][j][r] + skip_in[idx] * skip_w[col];
        }
      }
    }
  }
}

// ---------------- chunked scan over T (vectorized x2-h, L=64, C=64) --------
// Bu layout: [(b*4096 + t) * 2048 + h] re-plane (h<1024), +1024 im-plane.
// Thread handles h pair (2*h2, 2*h2+1): uint loads = 2 bf16 per plane.
// tid = b*(64*512) + c*512 + h2;  threads = 131072.

__global__ void scan_finals(const unsigned short* __restrict__ Bu,
                            const float* __restrict__ lam,
                            float4* __restrict__ finals4)
{
  int tid = blockIdx.x * 256 + threadIdx.x;
  int h2 = tid & 511, c = (tid >> 9) & 63, b = tid >> 15;
  int h0 = h2 * 2;
  float2 lre = *(const float2*)&lam[h0];
  float2 lim = *(const float2*)&lam[1024 + h0];
  const unsigned short* p = Bu + ((size_t)(b * 4096 + c * 64) * 2048) + h0;
  float y0re = 0.f, y0im = 0.f, y1re = 0.f, y1im = 0.f;
#pragma unroll 4
  for (int t = 0; t < 64; ++t) {
    unsigned ure = *(const unsigned*)(p);
    unsigned uim = *(const unsigned*)(p + 1024);
    float u0re = bf2f((unsigned short)ure), u1re = bf2f((unsigned short)(ure >> 16));
    float u0im = bf2f((unsigned short)uim), u1im = bf2f((unsigned short)(uim >> 16));
    float n0re = fmaf(lre.x, y0re, fmaf(-lim.x, y0im, u0re));
    float n0im = fmaf(lre.x, y0im, fmaf(lim.x, y0re, u0im));
    float n1re = fmaf(lre.y, y1re, fmaf(-lim.y, y1im, u1re));
    float n1im = fmaf(lre.y, y1im, fmaf(lim.y, y1re, u1im));
    y0re = n0re; y0im = n0im; y1re = n1re; y1im = n1im;
    p += 2048;
  }
  finals4[tid] = make_float4(y0re, y0im, y1re, y1im);
}

__global__ void scan_carries(const float4* __restrict__ finals4,
                             const float* __restrict__ lamL,
                             float4* __restrict__ carry4)
{
  int tid = blockIdx.x * 256 + threadIdx.x;  // 2048 = B * 512
  int h2 = tid & 511, b = tid >> 9;
  int h0 = h2 * 2;
  float2 Lre = *(const float2*)&lamL[h0];
  float2 Lim = *(const float2*)&lamL[1024 + h0];
  float H0re = 0.f, H0im = 0.f, H1re = 0.f, H1im = 0.f;
  for (int c = 0; c < 64; ++c) {
    size_t i = ((size_t)(b * 64 + c) << 9) + h2;
    carry4[i] = make_float4(H0re, H0im, H1re, H1im);   // carry INTO chunk c
    float4 f = finals4[i];
    float n0re = fmaf(Lre.x, H0re, fmaf(-Lim.x, H0im, f.x));
    float n0im = fmaf(Lre.x, H0im, fmaf(Lim.x, H0re, f.y));
    float n1re = fmaf(Lre.y, H1re, fmaf(-Lim.y, H1im, f.z));
    float n1im = fmaf(Lre.y, H1im, fmaf(Lim.y, H1re, f.w));
    H0re = n0re; H0im = n0im; H1re = n1re; H1im = n1im;
  }
}

__global__ void scan_apply(const float* __restrict__ lam,
                           const float4* __restrict__ carry4,
                           unsigned short* __restrict__ Bu)  // in-place -> hs
{
  int tid = blockIdx.x * 256 + threadIdx.x;
  int h2 = tid & 511, c = (tid >> 9) & 63, b = tid >> 15;
  int h0 = h2 * 2;
  float2 lre = *(const float2*)&lam[h0];
  float2 lim = *(const float2*)&lam[1024 + h0];
  float4 cv = carry4[tid];
  float y0re = cv.x, y0im = cv.y, y1re = cv.z, y1im = cv.w;
  unsigned short* p = Bu + ((size_t)(b * 4096 + c * 64) * 2048) + h0;
#pragma unroll 4
  for (int t = 0; t < 64; ++t) {
    unsigned ure = *(const unsigned*)(p);
    unsigned uim = *(const unsigned*)(p + 1024);
    float u0re = bf2f((unsigned short)ure), u1re = bf2f((unsigned short)(ure >> 16));
    float u0im = bf2f((unsigned short)uim), u1im = bf2f((unsigned short)(uim >> 16));
    float n0re = fmaf(lre.x, y0re, fmaf(-lim.x, y0im, u0re));
    float n0im = fmaf(lre.x, y0im, fmaf(lim.x, y0re, u0im));
    float n1re = fmaf(lre.y, y1re, fmaf(-lim.y, y1im, u1re));
    float n1im = fmaf(lre.y, y1im, fmaf(lim.y, y1re, u1im));
    y0re = n0re; y0im = n0im; y1re = n1re; y1im = n1im;
    *(unsigned*)(p)        = (unsigned)f2bf(y0re) | ((unsigned)f2bf(y1re) << 16);
    *(unsigned*)(p + 1024) = (unsigned)f2bf(y0im) | ((unsigned)f2bf(y1im) << 16);
    p += 2048;
  }
}

// ---------------- launch ----------------

extern "C" void kernel_launch(void* const* d_in, const int* in_sizes, int n_in,
                              void* d_out, int out_size, void* d_ws, size_t ws_size,
                              hipStream_t stream)
{
  const float* inputs    = (const float*)d_in[0];
  const float* nu_log    = (const float*)d_in[1];
  const float* theta_log = (const float*)d_in[2];
  const float* B_re      = (const float*)d_in[3];
  const float* B_im      = (const float*)d_in[4];
  const float* C_re      = (const float*)d_in[5];
  const float* C_im      = (const float*)d_in[6];
  const float* D_skip    = (const float*)d_in[7];
  float* out = (float*)d_out;

  char* ws = (char*)d_ws;
  float* lam   = (float*)ws;            // 2048 f32
  float* lamL  = lam + 2048;            // 2048 f32 (lambda^64)
  float* gamma = lamL + 2048;           // 1024 f32
  unsigned short* inp_bf = (unsigned short*)(ws + (1 << 16));       // 16384x1024 bf16
  unsigned short* Bcat   = inp_bf + (size_t)16384 * 1024;           // 2048x1024
  unsigned short* Ccat   = Bcat   + (size_t)2048 * 1024;            // 1024x2048
  unsigned short* Bu     = Ccat   + (size_t)1024 * 2048;            // 16384x2048 (re|im), becomes hs in place
  float4* finals4 = (float4*)(Bu + (size_t)16384 * 2048);           // 131072 (2MB)
  float4* carry4  = finals4 + 131072;                               // 131072 (2MB)
  // total ws use ~112 MB

  prep_params<<<4,    256, 0, stream>>>(nu_log, theta_log, lam, lamL, gamma);
  prep_B     <<<8192, 256, 0, stream>>>(B_re, B_im, gamma, Bcat);
  prep_C     <<<8192, 256, 0, stream>>>(C_re, C_im, Ccat);
  conv_inputs<<<16384,256, 0, stream>>>(inputs, inp_bf);

  // GEMM1: Bu[bt, n] = inputs @ Bcat^T  (M=16384, N=2048, K=1024) -> 64x16 tiles
  gemm256_kernel<0><<<1024, 256, 0, stream>>>(
      inp_bf, Bcat, Bu, 16384, 2048, 1024, nullptr, nullptr);

  scan_finals <<<512, 256, 0, stream>>>(Bu, lam, finals4);
  scan_carries<<<8,   256, 0, stream>>>(finals4, lamL, carry4);
  scan_apply  <<<512, 256, 0, stream>>>(lam, carry4, Bu);   // Bu -> hs in place

  // GEMM2: out[bt, d] = hs @ Ccat^T + inputs * D_skip  (M=16384, N=1024, K=2048) -> 64x8 tiles
  gemm256_kernel<1><<<512, 256, 0, stream>>>(
      Bu, Ccat, out, 16384, 1024, 2048, inputs, D_skip);
}